// Round 1
// baseline (271.110 us; speedup 1.0000x reference)
//
#include <hip/hip_runtime.h>

// DualBiPlane: per point p, bilinear-interp (with wraparound) 16 channels from
// Fxy[m, ., ., .] at (ind_hx, ind_hy) and 16 channels from Fuv[m, ., ., .] at
// (ind_u, ind_v); output is [N, 32] f32 = concat(lat_xy, lat_uv).
//
// Layout: 8 lanes per point. sub = t&7. sub<4 -> Fxy plane, channels sub*4..+3;
// sub>=4 -> Fuv plane, channels (sub-4)*4..+3. Output index = p*32 + sub*4 = 4t,
// so stores are perfectly coalesced float4 across the grid.

constexpr int RES = 400;                       // HX = HY = U_RES = V_RES
constexpr int LCH = 16;                        // LXY = LUV
constexpr long long PLANE_STRIDE = (long long)RES * RES * LCH;

__global__ __launch_bounds__(256) void dualbiplane_kernel(
    const int* __restrict__ mArr,
    const float* __restrict__ h,
    const float* __restrict__ u,
    const float* __restrict__ v,
    const float* __restrict__ Fxy,
    const float* __restrict__ Fuv,
    float* __restrict__ out,
    int N)
{
    long long t = (long long)blockIdx.x * blockDim.x + threadIdx.x;
    int p = (int)(t >> 3);
    if (p >= N) return;
    int sub = (int)(t & 7);

    int mi = mArr[p];

    float fi, fj;
    const float* __restrict__ F;
    if (sub < 4) {
        // ind_hx = (h0 + 1) / 2 * 400 ; ind_hy = (h1 + 1) / 2 * 400
        float2 hh = *reinterpret_cast<const float2*>(h + 2ll * p);
        fi = (hh.x + 1.0f) * 0.5f * (float)RES;
        fj = (hh.y + 1.0f) * 0.5f * (float)RES;
        F = Fxy;
    } else {
        fi = u[p] * (float)RES;
        fj = v[p] * (float)RES;
        F = Fuv;
    }
    // reference: where(ind == RES, RES-1, ind)
    if (fi == (float)RES) fi = (float)(RES - 1);
    if (fj == (float)RES) fj = (float)(RES - 1);

    int i1 = (int)fi;                  // fi >= 0 so trunc == floor
    int j1 = (int)fj;
    float ir = fi - (float)i1;
    float jr = fj - (float)j1;
    int i2 = (i1 + 1 == RES) ? 0 : i1 + 1;   // (i1+1) % RES
    int j2 = (j1 + 1 == RES) ? 0 : j1 + 1;

    int c = (sub & 3) * 4;             // channel group within the 16
    const float* __restrict__ Fb = F + (long long)mi * PLANE_STRIDE + c;

    const float4 g00 = *reinterpret_cast<const float4*>(Fb + ((long long)i1 * RES + j1) * LCH);
    const float4 g10 = *reinterpret_cast<const float4*>(Fb + ((long long)i2 * RES + j1) * LCH);
    const float4 g01 = *reinterpret_cast<const float4*>(Fb + ((long long)i1 * RES + j2) * LCH);
    const float4 g11 = *reinterpret_cast<const float4*>(Fb + ((long long)i2 * RES + j2) * LCH);

    float omi = 1.0f - ir, omj = 1.0f - jr;
    float4 r;
    r.x = (g00.x * omi + g10.x * ir) * omj + (g01.x * omi + g11.x * ir) * jr;
    r.y = (g00.y * omi + g10.y * ir) * omj + (g01.y * omi + g11.y * ir) * jr;
    r.z = (g00.z * omi + g10.z * ir) * omj + (g01.z * omi + g11.z * ir) * jr;
    r.w = (g00.w * omi + g10.w * ir) * omj + (g01.w * omi + g11.w * ir) * jr;

    *reinterpret_cast<float4*>(out + t * 4) = r;
}

extern "C" void kernel_launch(void* const* d_in, const int* in_sizes, int n_in,
                              void* d_out, int out_size, void* d_ws, size_t ws_size,
                              hipStream_t stream)
{
    const int*   m   = (const int*)d_in[0];
    const float* h   = (const float*)d_in[1];
    const float* u   = (const float*)d_in[2];
    const float* v   = (const float*)d_in[3];
    const float* Fxy = (const float*)d_in[4];
    const float* Fuv = (const float*)d_in[5];
    float* out = (float*)d_out;

    int N = in_sizes[0];
    long long total = (long long)N * 8;
    int block = 256;
    long long grid = (total + block - 1) / block;
    dualbiplane_kernel<<<(unsigned)grid, block, 0, stream>>>(m, h, u, v, Fxy, Fuv, out, N);
}

// Round 3
// 267.770 us; speedup vs baseline: 1.0125x; 1.0125x over previous
//
#include <hip/hip_runtime.h>

// DualBiPlane: per point p, bilinear-interp (wraparound) 16 channels from
// Fxy[m] at (ind_hx, ind_hy) and 16 from Fuv[m] at (ind_u, ind_v).
// Output [N, 32] f32 = concat(lat_xy, lat_uv).
//
// Layout: 8 lanes per point. sub = t&7. sub<4 -> Fxy, channels sub*4..+3;
// sub>=4 -> Fuv, channels (sub-4)*4..+3. Output index = 4t -> coalesced
// float4 stores.
//
// R3: non-temporal output stores + nt streaming coord loads, using a native
// ext_vector_type float4 (the builtin rejects HIP_vector_type). Goal: stop
// the 268 MB write stream from evicting the 82 MB of plane data so gathers
// hit L3 instead of going to HBM (R1 showed FETCH_SIZE ~774 MB).

constexpr int RES = 400;                       // HX = HY = U_RES = V_RES
constexpr int LCH = 16;                        // LXY = LUV
constexpr long long PLANE_STRIDE = (long long)RES * RES * LCH;

typedef float f32x4 __attribute__((ext_vector_type(4)));

__global__ __launch_bounds__(256) void dualbiplane_kernel(
    const int* __restrict__ mArr,
    const float* __restrict__ h,
    const float* __restrict__ u,
    const float* __restrict__ v,
    const float* __restrict__ Fxy,
    const float* __restrict__ Fuv,
    float* __restrict__ out,
    int N)
{
    long long t = (long long)blockIdx.x * blockDim.x + threadIdx.x;
    int p = (int)(t >> 3);
    if (p >= N) return;
    int sub = (int)(t & 7);

    int mi = __builtin_nontemporal_load(mArr + p);

    float fi, fj;
    const float* __restrict__ F;
    if (sub < 4) {
        // ind_hx = (h0 + 1) / 2 * 400 ; ind_hy = (h1 + 1) / 2 * 400
        float hx = __builtin_nontemporal_load(h + 2ll * p);
        float hy = __builtin_nontemporal_load(h + 2ll * p + 1);
        fi = (hx + 1.0f) * 0.5f * (float)RES;
        fj = (hy + 1.0f) * 0.5f * (float)RES;
        F = Fxy;
    } else {
        fi = __builtin_nontemporal_load(u + p) * (float)RES;
        fj = __builtin_nontemporal_load(v + p) * (float)RES;
        F = Fuv;
    }
    // reference: where(ind == RES, RES-1, ind)
    if (fi == (float)RES) fi = (float)(RES - 1);
    if (fj == (float)RES) fj = (float)(RES - 1);

    int i1 = (int)fi;                  // fi >= 0 so trunc == floor
    int j1 = (int)fj;
    float ir = fi - (float)i1;
    float jr = fj - (float)j1;
    int i2 = (i1 + 1 == RES) ? 0 : i1 + 1;   // (i1+1) % RES
    int j2 = (j1 + 1 == RES) ? 0 : j1 + 1;

    int c = (sub & 3) * 4;             // channel group within the 16
    const float* __restrict__ Fb = F + (long long)mi * PLANE_STRIDE + c;

    const f32x4 g00 = *reinterpret_cast<const f32x4*>(Fb + ((long long)i1 * RES + j1) * LCH);
    const f32x4 g10 = *reinterpret_cast<const f32x4*>(Fb + ((long long)i2 * RES + j1) * LCH);
    const f32x4 g01 = *reinterpret_cast<const f32x4*>(Fb + ((long long)i1 * RES + j2) * LCH);
    const f32x4 g11 = *reinterpret_cast<const f32x4*>(Fb + ((long long)i2 * RES + j2) * LCH);

    float omi = 1.0f - ir, omj = 1.0f - jr;
    f32x4 r = (g00 * omi + g10 * ir) * omj + (g01 * omi + g11 * ir) * jr;

    __builtin_nontemporal_store(r, reinterpret_cast<f32x4*>(out + t * 4));
}

extern "C" void kernel_launch(void* const* d_in, const int* in_sizes, int n_in,
                              void* d_out, int out_size, void* d_ws, size_t ws_size,
                              hipStream_t stream)
{
    const int*   m   = (const int*)d_in[0];
    const float* h   = (const float*)d_in[1];
    const float* u   = (const float*)d_in[2];
    const float* v   = (const float*)d_in[3];
    const float* Fxy = (const float*)d_in[4];
    const float* Fuv = (const float*)d_in[5];
    float* out = (float*)d_out;

    int N = in_sizes[0];
    long long total = (long long)N * 8;
    int block = 256;
    long long grid = (total + block - 1) / block;
    dualbiplane_kernel<<<(unsigned)grid, block, 0, stream>>>(m, h, u, v, Fxy, Fuv, out, N);
}